// Round 1
// baseline (149.801 us; speedup 1.0000x reference)
//
#include <hip/hip_runtime.h>
#include <hip/hip_bf16.h>

typedef __attribute__((ext_vector_type(4))) float f32x4;
typedef __attribute__((ext_vector_type(8))) short s16x8;

#define NB 131072
#define ND 8
#define NH 128
#define BLOCK_ROWS 128
#define W2S 136   // padded bf16 row stride for the W2 LDS tile (16B-aligned rows, conflict-free-ish)

__device__ __forceinline__ unsigned short f2bf(float f){
  unsigned u = __float_as_uint(f);
  u += 0x7fffu + ((u >> 16) & 1u);   // RTNE
  return (unsigned short)(u >> 16);
}

__global__ __launch_bounds__(256) void cvt_w2_kernel(const float4* __restrict__ src,
                                                     uint2* __restrict__ dst){
  int i = blockIdx.x * 256 + threadIdx.x;   // 32768 float4s total
  float4 v = src[i];
  uint2 o;
  o.x = (unsigned)f2bf(v.x) | ((unsigned)f2bf(v.y) << 16);
  o.y = (unsigned)f2bf(v.z) | ((unsigned)f2bf(v.w) << 16);
  dst[i] = o;
}

__global__ __launch_bounds__(256) void cond_embed_kernel(
    const float* __restrict__ labels,
    const float* __restrict__ emb_w,
    const float* __restrict__ w1,
    const float* __restrict__ b1,
    const unsigned short* __restrict__ w2b,
    const int* __restrict__ uncond_p,
    float* __restrict__ out)
{
  __shared__ __align__(16) unsigned short lds_w2[NH * W2S];     // 34816 B
  __shared__ __align__(16) float lds_labels[BLOCK_ROWS * ND];   // 4096 B
  __shared__ __align__(16) float lds_w1[ND * NH];               // 4096 B
  __shared__ __align__(16) float lds_b1[ND * NH];               // 4096 B
  __shared__ __align__(16) unsigned short lds_embT[NH * 8];     // 2048 B  embT[n][d]

  const int tid  = threadIdx.x;
  const int wave = tid >> 6;
  const int lane = tid & 63;
  const int quad = lane >> 4;
  const int l16  = lane & 15;
  const int uncond = uncond_p[0];
  const int blockbase = blockIdx.x * BLOCK_ROWS;

  // stage labels: 128 rows * 8 = 1024 floats = 256 float4
  {
    const float4* src = (const float4*)(labels + blockbase * ND);
    ((float4*)lds_labels)[tid] = src[tid];
  }
  // w1 / b1: 1024 floats each = 256 float4 each
  ((float4*)lds_w1)[tid] = ((const float4*)w1)[tid];
  ((float4*)lds_b1)[tid] = ((const float4*)b1)[tid];
  // embT bf16 [n][d]: lane n packs emb_w[0..7][n]
  if (tid < NH){
    unsigned e0 = f2bf(emb_w[0*NH + tid]), e1 = f2bf(emb_w[1*NH + tid]);
    unsigned e2 = f2bf(emb_w[2*NH + tid]), e3 = f2bf(emb_w[3*NH + tid]);
    unsigned e4 = f2bf(emb_w[4*NH + tid]), e5 = f2bf(emb_w[5*NH + tid]);
    unsigned e6 = f2bf(emb_w[6*NH + tid]), e7 = f2bf(emb_w[7*NH + tid]);
    uint4 v;
    v.x = e0 | (e1 << 16);  v.y = e2 | (e3 << 16);
    v.z = e4 | (e5 << 16);  v.w = e6 | (e7 << 16);
    ((uint4*)lds_embT)[tid] = v;
  }

  f32x4 acc[2][8];
  #pragma unroll
  for (int mt = 0; mt < 2; ++mt)
    #pragma unroll
    for (int nt = 0; nt < 8; ++nt)
      acc[mt][nt] = (f32x4){0.f, 0.f, 0.f, 0.f};

  for (int d = 0; d < ND; ++d){
    __syncthreads();  // protect previous d's tile until everyone is done
    {
      const uint4* src = (const uint4*)(w2b + d * (NH * NH));
      #pragma unroll
      for (int c = tid; c < 2048; c += 256){   // 2048 chunks of 8 bf16
        int n = c >> 4, cc = c & 15;
        *((uint4*)&lds_w2[n * W2S + cc * 8]) = src[c];
      }
    }
    __syncthreads();

    // A fragments (unnormalized softmax numerators) + per-row 1/Z
    s16x8 afrag[2][4];
    float zr[2][4];
    #pragma unroll
    for (int mt = 0; mt < 2; ++mt){
      int rib = wave * 32 + mt * 16 + l16;
      float x = lds_labels[rib * ND + d];
      bool drop = (uncond != 0) || (x != x);
      float xs = drop ? 0.f : x;
      float zp = 0.f;
      #pragma unroll
      for (int t = 0; t < 4; ++t){
        int kb = t * 32 + quad * 8;
        const float* w1p = &lds_w1[d * NH + kb];
        const float* b1p = &lds_b1[d * NH + kb];
        s16x8 a;
        #pragma unroll
        for (int j = 0; j < 8; ++j){
          float e = __expf(fmaf(xs, w1p[j], b1p[j]));
          zp += e;
          a[j] = (short)f2bf(e);
        }
        afrag[mt][t] = a;
      }
      zp += __shfl_xor(zp, 16);
      zp += __shfl_xor(zp, 32);
      float zinv = drop ? 0.f : (1.0f / zp);
      #pragma unroll
      for (int r = 0; r < 4; ++r) zr[mt][r] = __shfl(zinv, quad * 4 + r);
    }

    // GEMM: per n-tile, 4 k-step MFMA chain into temp, then scale-add by 1/Z
    #pragma unroll
    for (int nt = 0; nt < 8; ++nt){
      const unsigned short* bb = &lds_w2[(nt * 16 + l16) * W2S + quad * 8];
      f32x4 t0 = (f32x4){0.f,0.f,0.f,0.f};
      f32x4 t1 = (f32x4){0.f,0.f,0.f,0.f};
      #pragma unroll
      for (int t = 0; t < 4; ++t){
        s16x8 b = *((const s16x8*)(bb + t * 32));
        t0 = __builtin_amdgcn_mfma_f32_16x16x32_bf16(afrag[0][t], b, t0, 0, 0, 0);
        t1 = __builtin_amdgcn_mfma_f32_16x16x32_bf16(afrag[1][t], b, t1, 0, 0, 0);
      }
      #pragma unroll
      for (int r = 0; r < 4; ++r){
        acc[0][nt][r] = fmaf(t0[r], zr[0][r], acc[0][nt][r]);
        acc[1][nt][r] = fmaf(t1[r], zr[1][r], acc[1][nt][r]);
      }
    }
  }

  // Embedding fallback: one extra MFMA per (mt, nt).
  // A_extra[m][k=d] = drop ? 1 : 0 (quad 0 holds k=0..7); B_extra[k=d][n] = emb_w[d][n].
  s16x8 aex[2];
  #pragma unroll
  for (int mt = 0; mt < 2; ++mt){
    s16x8 a = (s16x8){0,0,0,0,0,0,0,0};
    if (quad == 0){
      int rib = wave * 32 + mt * 16 + l16;
      #pragma unroll
      for (int j = 0; j < 8; ++j){
        float x = lds_labels[rib * ND + j];
        bool drop = (uncond != 0) || (x != x);
        a[j] = drop ? (short)0x3F80 : (short)0;   // bf16 1.0
      }
    }
    aex[mt] = a;
  }
  #pragma unroll
  for (int nt = 0; nt < 8; ++nt){
    s16x8 b = (s16x8){0,0,0,0,0,0,0,0};
    if (quad == 0) b = *((const s16x8*)&lds_embT[(nt * 16 + l16) * 8]);
    acc[0][nt] = __builtin_amdgcn_mfma_f32_16x16x32_bf16(aex[0], b, acc[0][nt], 0, 0, 0);
    acc[1][nt] = __builtin_amdgcn_mfma_f32_16x16x32_bf16(aex[1], b, acc[1][nt], 0, 0, 0);
  }

  // epilogue: C layout col = lane&15, row = quad*4 + reg
  #pragma unroll
  for (int mt = 0; mt < 2; ++mt){
    #pragma unroll
    for (int nt = 0; nt < 8; ++nt){
      #pragma unroll
      for (int r = 0; r < 4; ++r){
        int row = blockbase + wave * 32 + mt * 16 + quad * 4 + r;
        out[row * NH + nt * 16 + l16] = acc[mt][nt][r];
      }
    }
  }
}

extern "C" void kernel_launch(void* const* d_in, const int* in_sizes, int n_in,
                              void* d_out, int out_size, void* d_ws, size_t ws_size,
                              hipStream_t stream){
  const float* labels = (const float*)d_in[0];
  const float* emb_w  = (const float*)d_in[1];
  const float* w1     = (const float*)d_in[2];
  const float* b1     = (const float*)d_in[3];
  const float* w2     = (const float*)d_in[4];
  const int*   uncond = (const int*)d_in[6];
  (void)in_sizes; (void)n_in; (void)out_size; (void)ws_size;

  float* out = (float*)d_out;
  unsigned short* w2b = (unsigned short*)d_ws;   // 131072 bf16 = 256 KB scratch

  cvt_w2_kernel<<<128, 256, 0, stream>>>((const float4*)w2, (uint2*)w2b);
  cond_embed_kernel<<<NB / BLOCK_ROWS, 256, 0, stream>>>(labels, emb_w, w1, b1, w2b, uncond, out);
}

// Round 2
// 132.648 us; speedup vs baseline: 1.1293x; 1.1293x over previous
//
#include <hip/hip_runtime.h>
#include <hip/hip_bf16.h>

typedef __attribute__((ext_vector_type(4))) float f32x4;
typedef __attribute__((ext_vector_type(4))) int   i32x4;
typedef __attribute__((ext_vector_type(8))) short s16x8;

#define NB 131072
#define ND 8
#define NH 128
#define BROWS 128

#if __has_builtin(__builtin_amdgcn_exp2f)
#define EXP2F(x) __builtin_amdgcn_exp2f(x)
#define PRESCALE 1.4426950408889634f
#else
#define EXP2F(x) __expf(x)
#define PRESCALE 1.0f
#endif

#if __has_builtin(__builtin_amdgcn_rcpf)
#define RCPF(x) __builtin_amdgcn_rcpf(x)
#else
#define RCPF(x) (1.0f / (x))
#endif

__device__ __forceinline__ unsigned short f2bf(float f){
  unsigned u = __float_as_uint(f);
  u += 0x7fffu + ((u >> 16) & 1u);   // RTNE
  return (unsigned short)(u >> 16);
}

// pack two f32 -> one dword of 2 bf16 (truncation) in a single v_perm_b32
__device__ __forceinline__ unsigned pk2(float lo, float hi){
  return __builtin_amdgcn_perm(__float_as_uint(hi), __float_as_uint(lo), 0x07060302u);
}

// w2 [d][k_out=n][h=k] f32  ->  bf16 chunks [d][kb=k/8][n][8] (k-major 16B chunks)
__global__ __launch_bounds__(256) void cvt_w2_kernel(const float* __restrict__ src,
                                                     uint4* __restrict__ dst){
  int i = blockIdx.x * 256 + threadIdx.x;         // 16384 chunks
  int d = i >> 11, kb = (i >> 7) & 15, n = i & 127;
  const float* s = src + ((d * 128 + n) * 128 + kb * 8);
  float4 v0 = ((const float4*)s)[0];
  float4 v1 = ((const float4*)s)[1];
  uint4 o;
  o.x = (unsigned)f2bf(v0.x) | ((unsigned)f2bf(v0.y) << 16);
  o.y = (unsigned)f2bf(v0.z) | ((unsigned)f2bf(v0.w) << 16);
  o.z = (unsigned)f2bf(v1.x) | ((unsigned)f2bf(v1.y) << 16);
  o.w = (unsigned)f2bf(v1.z) | ((unsigned)f2bf(v1.w) << 16);
  dst[i] = o;
}

__global__ __launch_bounds__(256, 3) void cond_embed_kernel(
    const float* __restrict__ labels,
    const float* __restrict__ emb_w,
    const float* __restrict__ w1,
    const float* __restrict__ b1,
    const unsigned short* __restrict__ w2b,
    const int* __restrict__ uncond_p,
    float* __restrict__ out)
{
  __shared__ __align__(16) unsigned short lds_w2[NH * NH];   // 32 KB k-major chunks
  __shared__ __align__(16) float lds_lab[ND * BROWS];        // 4 KB, transposed [d][row]
  __shared__ __align__(16) float lds_w1[ND * NH];            // 4 KB, pre-scaled by log2e
  __shared__ __align__(16) float lds_b1[ND * NH];            // 4 KB, pre-scaled by log2e
  __shared__ __align__(16) unsigned short lds_embT[NH * 8];  // 2 KB, embT[n][d] bf16

  const int tid  = threadIdx.x;
  const int wave = tid >> 6;
  const int lane = tid & 63;
  const int quad = lane >> 4;
  const int l16  = lane & 15;
  const int uncond = uncond_p[0];
  const int blockbase = blockIdx.x * BROWS;

  // labels -> LDS transposed [d][row]
  {
    float4 v = ((const float4*)(labels + blockbase * ND))[tid];
    int row = tid >> 1, dbase = (tid & 1) * 4;
    lds_lab[(dbase + 0) * BROWS + row] = v.x;
    lds_lab[(dbase + 1) * BROWS + row] = v.y;
    lds_lab[(dbase + 2) * BROWS + row] = v.z;
    lds_lab[(dbase + 3) * BROWS + row] = v.w;
  }
  // w1/b1 pre-scaled into LDS
  {
    float4 a = ((const float4*)w1)[tid];
    float4 b = ((const float4*)b1)[tid];
    ((float4*)lds_w1)[tid] = (float4){a.x * PRESCALE, a.y * PRESCALE, a.z * PRESCALE, a.w * PRESCALE};
    ((float4*)lds_b1)[tid] = (float4){b.x * PRESCALE, b.y * PRESCALE, b.z * PRESCALE, b.w * PRESCALE};
  }
  if (tid < NH){
    unsigned e0 = f2bf(emb_w[0*NH + tid]), e1 = f2bf(emb_w[1*NH + tid]);
    unsigned e2 = f2bf(emb_w[2*NH + tid]), e3 = f2bf(emb_w[3*NH + tid]);
    unsigned e4 = f2bf(emb_w[4*NH + tid]), e5 = f2bf(emb_w[5*NH + tid]);
    unsigned e6 = f2bf(emb_w[6*NH + tid]), e7 = f2bf(emb_w[7*NH + tid]);
    uint4 v;
    v.x = e0 | (e1 << 16);  v.y = e2 | (e3 << 16);
    v.z = e4 | (e5 << 16);  v.w = e6 | (e7 << 16);
    ((uint4*)lds_embT)[tid] = v;
  }

  f32x4 acc[2][8];
  #pragma unroll
  for (int mt = 0; mt < 2; ++mt)
    #pragma unroll
    for (int nt = 0; nt < 8; ++nt)
      acc[mt][nt] = (f32x4){0.f, 0.f, 0.f, 0.f};

  const s16x8 bones = (s16x8)((short)0x3F80);   // bf16 1.0 broadcast

  for (int d = 0; d < ND; ++d){
    __syncthreads();   // previous tile consumed (also covers initial stages at d=0)
    {
      const unsigned short* g = w2b + d * (NH * NH);
      #pragma unroll
      for (int i = 0; i < 8; ++i){
        int idx = tid + i * 256;   // 16B chunk id, 2048 chunks = 32 KB
        __builtin_amdgcn_global_load_lds(
            (const __attribute__((address_space(1))) void*)(g + idx * 8),
            (__attribute__((address_space(3))) void*)(lds_w2 + idx * 8),
            16, 0, 0);
      }
    }
    __syncthreads();

    // A fragments: unnormalized softmax numerators, packed bf16 (truncation)
    s16x8 afrag[2][4];
    f32x4 zr[2];       // per-C-row 1/Z (0 if dropped)
    #pragma unroll
    for (int mt = 0; mt < 2; ++mt){
      int rib = wave * 32 + mt * 16 + l16;
      float x = lds_lab[d * BROWS + rib];
      bool dropA = (uncond != 0) || (x != x);
      float xs = dropA ? 0.f : x;
      #pragma unroll
      for (int t = 0; t < 4; ++t){
        const float* w1p = &lds_w1[d * NH + t * 32 + quad * 8];
        const float* b1p = &lds_b1[d * NH + t * 32 + quad * 8];
        float e0 = EXP2F(fmaf(xs, w1p[0], b1p[0]));
        float e1 = EXP2F(fmaf(xs, w1p[1], b1p[1]));
        float e2 = EXP2F(fmaf(xs, w1p[2], b1p[2]));
        float e3 = EXP2F(fmaf(xs, w1p[3], b1p[3]));
        float e4 = EXP2F(fmaf(xs, w1p[4], b1p[4]));
        float e5 = EXP2F(fmaf(xs, w1p[5], b1p[5]));
        float e6 = EXP2F(fmaf(xs, w1p[6], b1p[6]));
        float e7 = EXP2F(fmaf(xs, w1p[7], b1p[7]));
        i32x4 ai;
        ai[0] = (int)pk2(e0, e1);
        ai[1] = (int)pk2(e2, e3);
        ai[2] = (int)pk2(e4, e5);
        ai[3] = (int)pk2(e6, e7);
        afrag[mt][t] = __builtin_bit_cast(s16x8, ai);
      }
      // Z per row via ones-column MFMA: C_z[m][n] = sum_k e[m,k]  (C layout!)
      f32x4 z = (f32x4){0.f, 0.f, 0.f, 0.f};
      #pragma unroll
      for (int t = 0; t < 4; ++t)
        z = __builtin_amdgcn_mfma_f32_16x16x32_bf16(afrag[mt][t], bones, z, 0, 0, 0);
      // drop mask in C layout: rows quad*4 + r
      float4 xc = *(const float4*)&lds_lab[d * BROWS + wave * 32 + mt * 16 + quad * 4];
      f32x4 zi;
      zi[0] = ((uncond != 0) || (xc.x != xc.x)) ? 0.f : RCPF(z[0]);
      zi[1] = ((uncond != 0) || (xc.y != xc.y)) ? 0.f : RCPF(z[1]);
      zi[2] = ((uncond != 0) || (xc.z != xc.z)) ? 0.f : RCPF(z[2]);
      zi[3] = ((uncond != 0) || (xc.w != xc.w)) ? 0.f : RCPF(z[3]);
      zr[mt] = zi;
    }

    // GEMM: per n-tile 4-step MFMA chain into temp, then scale-add by 1/Z
    #pragma unroll
    for (int nt = 0; nt < 8; ++nt){
      const unsigned short* bb = lds_w2 + (quad * NH + nt * 16 + l16) * 8;
      f32x4 t0 = (f32x4){0.f,0.f,0.f,0.f};
      f32x4 t1 = (f32x4){0.f,0.f,0.f,0.f};
      #pragma unroll
      for (int t = 0; t < 4; ++t){
        s16x8 b = *((const s16x8*)(bb + t * 4 * NH * 8));
        t0 = __builtin_amdgcn_mfma_f32_16x16x32_bf16(afrag[0][t], b, t0, 0, 0, 0);
        t1 = __builtin_amdgcn_mfma_f32_16x16x32_bf16(afrag[1][t], b, t1, 0, 0, 0);
      }
      #pragma unroll
      for (int r = 0; r < 4; ++r){
        acc[0][nt][r] = fmaf(t0[r], zr[0][r], acc[0][nt][r]);
        acc[1][nt][r] = fmaf(t1[r], zr[1][r], acc[1][nt][r]);
      }
    }
  }

  // Embedding fallback: A_extra[m][k=d] = drop?1:0 (quad 0), B_extra[k=d][n] = emb_w[d][n]
  s16x8 aex[2];
  #pragma unroll
  for (int mt = 0; mt < 2; ++mt){
    s16x8 a = (s16x8)((short)0);
    if (quad == 0){
      int rib = wave * 32 + mt * 16 + l16;
      #pragma unroll
      for (int j = 0; j < 8; ++j){
        float x = lds_lab[j * BROWS + rib];
        bool drop = (uncond != 0) || (x != x);
        a[j] = drop ? (short)0x3F80 : (short)0;
      }
    }
    aex[mt] = a;
  }
  #pragma unroll
  for (int nt = 0; nt < 8; ++nt){
    s16x8 b = (s16x8)((short)0);
    if (quad == 0) b = *((const s16x8*)&lds_embT[(nt * 16 + l16) * 8]);
    acc[0][nt] = __builtin_amdgcn_mfma_f32_16x16x32_bf16(aex[0], b, acc[0][nt], 0, 0, 0);
    acc[1][nt] = __builtin_amdgcn_mfma_f32_16x16x32_bf16(aex[1], b, acc[1][nt], 0, 0, 0);
  }

  // epilogue store: C layout col = l16, row = quad*4 + r
  #pragma unroll
  for (int mt = 0; mt < 2; ++mt){
    #pragma unroll
    for (int nt = 0; nt < 8; ++nt){
      #pragma unroll
      for (int r = 0; r < 4; ++r){
        int row = blockbase + wave * 32 + mt * 16 + quad * 4 + r;
        out[row * NH + nt * 16 + l16] = acc[mt][nt][r];
      }
    }
  }
}

extern "C" void kernel_launch(void* const* d_in, const int* in_sizes, int n_in,
                              void* d_out, int out_size, void* d_ws, size_t ws_size,
                              hipStream_t stream){
  const float* labels = (const float*)d_in[0];
  const float* emb_w  = (const float*)d_in[1];
  const float* w1     = (const float*)d_in[2];
  const float* b1     = (const float*)d_in[3];
  const float* w2     = (const float*)d_in[4];
  const int*   uncond = (const int*)d_in[6];
  (void)in_sizes; (void)n_in; (void)out_size; (void)ws_size;

  float* out = (float*)d_out;
  unsigned short* w2b = (unsigned short*)d_ws;   // 131072 bf16 = 256 KB scratch

  cvt_w2_kernel<<<64, 256, 0, stream>>>(w2, (uint4*)w2b);
  cond_embed_kernel<<<NB / BROWS, 256, 0, stream>>>(labels, emb_w, w1, b1, w2b, uncond, out);
}